// Round 3
// baseline (737.624 us; speedup 1.0000x reference)
//
#include <hip/hip_runtime.h>

#define NUM_LEVELS 16
#define LOG2_HASHMAP 19
#define TABLE_SIZE (1u << LOG2_HASHMAP)
#define HASH_MASK (TABLE_SIZE - 1u)
#define BASE_RES 16
#define N_QUERIES (1 << 20)
#define BLK 256
#define BLOCKS_PER_LEVEL (N_QUERIES / BLK)   // 4096 blocks per level, 1 query/thread

typedef float f2v __attribute__((ext_vector_type(2)));
typedef float f4v __attribute__((ext_vector_type(4)));

// Decode the `bound` scalar: harness stores Python int as int32, but guard
// against a float32 encoding too.
__device__ __forceinline__ float decode_bound(const void* p) {
    int iv = *(const int*)p;
    float fv = __int_as_float(iv);
    float afv = fabsf(fv);
    if (afv >= 1e-8f && afv <= 1e8f) return fv;   // plausible float encoding
    return (float)iv;                              // int encoding (expected)
}

// Level-major gather: grid = [NUM_LEVELS * BLOCKS_PER_LEVEL], level = blockIdx /
// BLOCKS_PER_LEVEL. Blocks dispatch in ~blockIdx order, so the resident window
// (~2048 blocks) covers ~1 level -> each XCD L2 holds the active level's table
// -> FETCH_SIZE at the compulsory-miss optimum (measured: 580 MB).
//
// Gather bottleneck (r0-r2 counters): 134M independent 8 B gathers, each a
// distinct 64 B line; ~0.4 L1-miss/cy/CU == per-XCD L2 request-rate wall.
// NOT HBM (16.6%), NOT VALU (8.8%), NOT occupancy (89%). Structural floor
// ~546 us. Left untouched.
//
// SESSION r3 EXPERIMENT: r1->r2 rewrote the transpose completely (strided ->
// LDS-staged) and total moved 732.4 -> 732.2 us: residual (~186 us) is
// INVARIANT to transpose internals. This round makes the 2nd kernel
// theoretically minimal (block-tiled ws => pure contiguous 32KB-in/32KB-out
// streaming permute) + nontemporal ws/out traffic (evict-first, shrinks
// kernel-end dirty-L2 writeback). If total still ~732, the residual is
// pipeline/harness overhead (flush + launch), not kernel work => fuse or stop.
//
// ws layout (USE_WS=true): BLOCK-TILED [chunk][level][256] float2 — each
// gather block writes one contiguous 2 KB run; each transpose block reads one
// contiguous 32 KB run.
template <bool USE_WS>
__global__ __launch_bounds__(BLK, 8)
void gather_kernel(const float* __restrict__ in,    // [N,3]
                   const float* __restrict__ emb,   // [L, T, 2]
                   const void*  __restrict__ bound_ptr,
                   float* __restrict__ dst)
{
    const unsigned P1 = 2654435761u, P2 = 805459861u;
    const int level = blockIdx.x / BLOCKS_PER_LEVEL;
    const int chunk = blockIdx.x % BLOCKS_PER_LEVEL;
    const int n = chunk * BLK + threadIdx.x;

    const float bound = decode_bound(bound_ptr);

    // channel permutation [2,0,1]: hash-dim0 = in[...,2], dim1 = in[...,0],
    // dim2 = in[...,1]
    float i0 = in[(size_t)n * 3 + 0];
    float i1 = in[(size_t)n * 3 + 1];
    float i2 = in[(size_t)n * 3 + 2];

    // u = (x / bound + 1) * 0.5 — forbid FMA contraction (floor() boundary
    // decisions at high res must match numpy bit-for-bit).
    float u0 = __fmul_rn(__fadd_rn(__fdiv_rn(i2, bound), 1.0f), 0.5f);
    float u1 = __fmul_rn(__fadd_rn(__fdiv_rn(i0, bound), 1.0f), 0.5f);
    float u2 = __fmul_rn(__fadd_rn(__fdiv_rn(i1, bound), 1.0f), 0.5f);

    float res = (float)(BASE_RES << level);   // floor(16 * 2^l) exact

    float p0 = __fadd_rn(__fmul_rn(u0, res), -0.5f);
    float p1 = __fadd_rn(__fmul_rn(u1, res), -0.5f);
    float p2 = __fadd_rn(__fmul_rn(u2, res), -0.5f);
    float g0 = floorf(p0), g1 = floorf(p1), g2 = floorf(p2);
    float fr0 = __fsub_rn(p0, g0), fr1 = __fsub_rn(p1, g1), fr2 = __fsub_rn(p2, g2);
    int c0 = (int)g0, c1 = (int)g1, c2 = (int)g2;

    // uint32 wraparound semantics, as jnp.uint32
    unsigned b0  = (unsigned)c0;            // prime 1
    unsigned b0p = b0 + 1u;
    unsigned b1  = (unsigned)c1 * P1;
    unsigned b1p = b1 + P1;
    unsigned b2  = (unsigned)c2 * P2;
    unsigned b2p = b2 + P2;

    const float2* tbl = (const float2*)emb + (size_t)level * TABLE_SIZE;

    unsigned idx[8];
    // corner c = i*4 + j*2 + k (i->dim0, j->dim1, k->dim2)
    idx[0] = (b0  ^ b1  ^ b2 ) & HASH_MASK;
    idx[1] = (b0  ^ b1  ^ b2p) & HASH_MASK;
    idx[2] = (b0  ^ b1p ^ b2 ) & HASH_MASK;
    idx[3] = (b0  ^ b1p ^ b2p) & HASH_MASK;
    idx[4] = (b0p ^ b1  ^ b2 ) & HASH_MASK;
    idx[5] = (b0p ^ b1  ^ b2p) & HASH_MASK;
    idx[6] = (b0p ^ b1p ^ b2 ) & HASH_MASK;
    idx[7] = (b0p ^ b1p ^ b2p) & HASH_MASK;

    float2 f[8];
    #pragma unroll
    for (int c = 0; c < 8; ++c) f[c] = tbl[idx[c]];   // 8 independent gathers

    float wx[2] = {1.0f - fr0, fr0};
    float wy[2] = {1.0f - fr1, fr1};
    float wz[2] = {1.0f - fr2, fr2};

    float a0 = 0.0f, a1 = 0.0f;
    #pragma unroll
    for (int c = 0; c < 8; ++c) {
        float w = wx[(c >> 2) & 1] * wy[(c >> 1) & 1] * wz[c & 1];
        a0 += f[c].x * w;
        a1 += f[c].y * w;
    }

    if (USE_WS) {
        // block-tiled [chunk][level][256]: this block's 256 float2 go to one
        // contiguous 2 KB run. Nontemporal: write-once, read-once-next-kernel
        // -> evict-first, minimizes kernel-end dirty-L2 writeback.
        size_t slot = ((size_t)chunk * NUM_LEVELS + level) * BLK + threadIdx.x;
        union { float2 f; unsigned long long u; } cv;
        cv.f = make_float2(a0, a1);
        __builtin_nontemporal_store(cv.u, (unsigned long long*)((float2*)dst + slot));
    } else {
        float2* o = (float2*)(dst + (size_t)n * 32 + 2 * level);
        *o = make_float2(a0, a1);
    }
}

// Permute-copy [chunk][L][256] float2 (ws, block-tiled) -> [N, 32] (out).
// Block c: reads ONE contiguous 32 KB run (16 x 256 float2, level rows),
// permutes through LDS, writes ONE contiguous 32 KB run of out — the
// theoretically minimal 2nd kernel (pure streaming, zero strided global
// access). Nontemporal on both sides (read-once / write-once).
//
// LDS [16][257] float2 = 32,896 B. Write phase: lane word-stride 2 -> 2-way
// (free, m136). Read phase: b64 reads land on even banks only -> ~4-way
// (1.58x on 16 LDS instrs — negligible vs streaming).
__global__ __launch_bounds__(BLK, 4)
void transpose_kernel(const float* __restrict__ ws, float* __restrict__ out)
{
    __shared__ float2 s[NUM_LEVELS][BLK + 1];
    const f2v* w = (const f2v*)ws + (size_t)blockIdx.x * (NUM_LEVELS * BLK);

    #pragma unroll
    for (int l = 0; l < NUM_LEVELS; ++l) {
        f2v v = __builtin_nontemporal_load(w + l * BLK + threadIdx.x);
        s[l][threadIdx.x] = make_float2(v.x, v.y);
    }
    __syncthreads();

    f4v* o = (f4v*)out + (size_t)blockIdx.x * (BLK * 8);   // 8 float4 / query
    #pragma unroll
    for (int r = 0; r < 8; ++r) {
        int t = r * BLK + (int)threadIdx.x;   // block-local float4 index
        int n = t >> 3;                       // query within block (0..255)
        int q = t & 7;                        // float4 = levels 2q, 2q+1
        float2 a = s[2 * q][n];
        float2 b = s[2 * q + 1][n];
        f4v v; v.x = a.x; v.y = a.y; v.z = b.x; v.w = b.y;
        __builtin_nontemporal_store(v, o + t);
    }
}

extern "C" void kernel_launch(void* const* d_in, const int* in_sizes, int n_in,
                              void* d_out, int out_size, void* d_ws, size_t ws_size,
                              hipStream_t stream) {
    const float* in   = (const float*)d_in[0];
    const float* emb  = (const float*)d_in[1];
    const void*  bptr = d_in[2];
    float* out = (float*)d_out;

    const size_t need = (size_t)N_QUERIES * NUM_LEVELS * 2 * sizeof(float); // 128 MiB
    dim3 block(BLK);
    dim3 ggrid(NUM_LEVELS * BLOCKS_PER_LEVEL);

    if (ws_size >= need) {
        float* ws = (float*)d_ws;
        gather_kernel<true><<<ggrid, block, 0, stream>>>(in, emb, bptr, ws);
        transpose_kernel<<<N_QUERIES / BLK, block, 0, stream>>>(ws, out);
    } else {
        gather_kernel<false><<<ggrid, block, 0, stream>>>(in, emb, bptr, out);
    }
}

// Round 4
// 645.164 us; speedup vs baseline: 1.1433x; 1.1433x over previous
//
#include <hip/hip_runtime.h>

#define NUM_LEVELS 16
#define LOG2_HASHMAP 19
#define TABLE_SIZE (1u << LOG2_HASHMAP)
#define HASH_MASK (TABLE_SIZE - 1u)
#define BASE_RES 16
#define N_QUERIES (1 << 20)
#define BLK 256
#define BLOCKS_PER_LEVEL (N_QUERIES / BLK)   // 4096 blocks per level, 1 query/thread

// Decode the `bound` scalar: harness stores Python int as int32, but guard
// against a float32 encoding too.
__device__ __forceinline__ float decode_bound(const void* p) {
    int iv = *(const int*)p;
    float fv = __int_as_float(iv);
    float afv = fabsf(fv);
    if (afv >= 1e-8f && afv <= 1e8f) return fv;   // plausible float encoding
    return (float)iv;                              // int encoding (expected)
}

// Level-major gather: grid = [NUM_LEVELS * BLOCKS_PER_LEVEL]. Blocks dispatch
// in ~blockIdx order -> resident window covers ~1 level -> per-XCD L2 holds
// the active level's 4 MiB table -> FETCH at compulsory optimum (~580 MB).
//
// SESSION LOG:
//  r0-r2: residual (total - gather) is INVARIANT (~170-190 us) across three
//    structurally different transposes -> transpose is not the lever.
//  r3: nontemporal ws stores + block-tiled layout REGRESSED gather 546->569
//    (codegen perturbation, VGPR 20->16) and absmax 0 -> 6e-5. Reverted.
//  r4 (this): cut the gather's L2 request count. Gather is request-rate
//    bound (~0.4 req/cy/CU; HBM 16.6%, VALU 9%, occ 89%). Hash structure:
//    dim0's prime is 1, so for EVEN c0 the two i-corners sit at adjacent
//    table entries {E, E^1} = one aligned float4. Even lanes: 4 float4 loads
//    (covers both i-corners); odd lanes: + 4 predicated float2 loads.
//    Avg 6 requests/query-level vs 8 (75%). Same 64B lines -> FETCH unchanged.
//
// USE_WS: write level-major [L][N][2] into workspace (coalesced 8 B/lane
// contiguous), transposed to [N,32] by a second kernel. Fallback (!USE_WS):
// strided float2 writes directly into out (correct, slower write path).
template <bool USE_WS>
__global__ __launch_bounds__(BLK, 8)
void gather_kernel(const float* __restrict__ in,    // [N,3]
                   const float* __restrict__ emb,   // [L, T, 2]
                   const void*  __restrict__ bound_ptr,
                   float* __restrict__ dst)
{
    const unsigned P1 = 2654435761u, P2 = 805459861u;
    const int level = blockIdx.x / BLOCKS_PER_LEVEL;
    const int chunk = blockIdx.x % BLOCKS_PER_LEVEL;
    const int n = chunk * BLK + threadIdx.x;

    const float bound = decode_bound(bound_ptr);

    // channel permutation [2,0,1]: hash-dim0 = in[...,2], dim1 = in[...,0],
    // dim2 = in[...,1]
    float i0 = in[(size_t)n * 3 + 0];
    float i1 = in[(size_t)n * 3 + 1];
    float i2 = in[(size_t)n * 3 + 2];

    // u = (x / bound + 1) * 0.5 — forbid FMA contraction (floor() boundary
    // decisions at high res must match numpy bit-for-bit).
    float u0 = __fmul_rn(__fadd_rn(__fdiv_rn(i2, bound), 1.0f), 0.5f);
    float u1 = __fmul_rn(__fadd_rn(__fdiv_rn(i0, bound), 1.0f), 0.5f);
    float u2 = __fmul_rn(__fadd_rn(__fdiv_rn(i1, bound), 1.0f), 0.5f);

    float res = (float)(BASE_RES << level);   // floor(16 * 2^l) exact

    float p0 = __fadd_rn(__fmul_rn(u0, res), -0.5f);
    float p1 = __fadd_rn(__fmul_rn(u1, res), -0.5f);
    float p2 = __fadd_rn(__fmul_rn(u2, res), -0.5f);
    float g0 = floorf(p0), g1 = floorf(p1), g2 = floorf(p2);
    float fr0 = __fsub_rn(p0, g0), fr1 = __fsub_rn(p1, g1), fr2 = __fsub_rn(p2, g2);
    int c0 = (int)g0, c1 = (int)g1, c2 = (int)g2;

    // uint32 wraparound semantics, as jnp.uint32
    unsigned b0  = (unsigned)c0;            // prime 1
    unsigned b0p = b0 + 1u;
    unsigned b1  = (unsigned)c1 * P1;
    unsigned b1p = b1 + P1;
    unsigned b2  = (unsigned)c2 * P2;
    unsigned b2p = b2 + P2;

    const float2* tbl  = (const float2*)emb + (size_t)level * TABLE_SIZE;
    const float4* tbl4 = (const float4*)tbl;

    // X[m], m = j*2 + k: the (j,k)-dependent part of the hash
    unsigned X[4];
    X[0] = b1  ^ b2;
    X[1] = b1  ^ b2p;
    X[2] = b1p ^ b2;
    X[3] = b1p ^ b2p;

    const bool odd = (b0 & 1u) != 0u;   // c0 parity decides i-corner adjacency

    // Phase 1: 4 aligned float4 loads — each covers corner (i=0) and, for
    // even c0, also corner (i=1) (entry E^1, same 16B pair, same 64B line).
    unsigned E0[4];
    float4 v4[4];
    #pragma unroll
    for (int m = 0; m < 4; ++m) {
        E0[m] = (b0 ^ X[m]) & HASH_MASK;
        v4[m] = tbl4[E0[m] >> 1];
    }

    // Phase 2: odd-c0 lanes fetch their i=1 corners (4 exec-masked loads).
    float2 fb[4] = {make_float2(0.f,0.f), make_float2(0.f,0.f),
                    make_float2(0.f,0.f), make_float2(0.f,0.f)};
    if (odd) {
        #pragma unroll
        for (int m = 0; m < 4; ++m)
            fb[m] = tbl[(b0p ^ X[m]) & HASH_MASK];
    }

    // Phase 3: assemble the 8 corner values (bit-exact selection, no math).
    float2 f[8];
    #pragma unroll
    for (int m = 0; m < 4; ++m) {
        bool hi = (E0[m] & 1u) != 0u;
        float2 lo2 = make_float2(v4[m].x, v4[m].y);
        float2 hi2 = make_float2(v4[m].z, v4[m].w);
        f[m]     = hi ? hi2 : lo2;                    // corner (0,j,k)
        f[4 + m] = odd ? fb[m] : (hi ? lo2 : hi2);    // corner (1,j,k)
    }

    // Accumulation: EXACT source structure of the absmax=0 r2 kernel
    // (c = i*4 + j*2 + k ordering preserved).
    float wx[2] = {1.0f - fr0, fr0};
    float wy[2] = {1.0f - fr1, fr1};
    float wz[2] = {1.0f - fr2, fr2};

    float a0 = 0.0f, a1 = 0.0f;
    #pragma unroll
    for (int c = 0; c < 8; ++c) {
        float w = wx[(c >> 2) & 1] * wy[(c >> 1) & 1] * wz[c & 1];
        a0 += f[c].x * w;
        a1 += f[c].y * w;
    }

    if (USE_WS) {
        // level-major [L][N][2]: wave writes 64 lanes x 8 B contiguous
        float2* o = (float2*)dst + (size_t)level * N_QUERIES + n;
        *o = make_float2(a0, a1);
    } else {
        float2* o = (float2*)(dst + (size_t)n * 32 + 2 * level);
        *o = make_float2(a0, a1);
    }
}

// Transpose [L][N][2] (ws) -> [N, 32] (out), LDS-staged (r2 version, part of
// the absmax=0 run). Block b stages queries n0..n0+255 of all 16 levels via
// contiguous 2 KB runs per level, then emits 32 KB of coalesced float4.
// LDS [16][257] float2 = 32,896 B.
__global__ __launch_bounds__(BLK, 4)
void transpose_kernel(const float* __restrict__ ws, float* __restrict__ out)
{
    __shared__ float2 s[NUM_LEVELS][BLK + 1];
    const int n0 = blockIdx.x * BLK;
    const float2* w = (const float2*)ws;

    #pragma unroll
    for (int l = 0; l < NUM_LEVELS; ++l) {
        s[l][threadIdx.x] = w[(size_t)l * N_QUERIES + n0 + threadIdx.x];
    }
    __syncthreads();

    float4* o = (float4*)out + (size_t)n0 * 8;   // 8 float4 per query
    #pragma unroll
    for (int r = 0; r < 8; ++r) {
        int t = r * BLK + (int)threadIdx.x;   // block-local float4 index
        int n = t >> 3;                       // query within block (0..255)
        int q = t & 7;                        // float4 = levels 2q, 2q+1
        float2 a = s[2 * q][n];
        float2 b = s[2 * q + 1][n];
        o[t] = make_float4(a.x, a.y, b.x, b.y);
    }
}

extern "C" void kernel_launch(void* const* d_in, const int* in_sizes, int n_in,
                              void* d_out, int out_size, void* d_ws, size_t ws_size,
                              hipStream_t stream) {
    const float* in   = (const float*)d_in[0];
    const float* emb  = (const float*)d_in[1];
    const void*  bptr = d_in[2];
    float* out = (float*)d_out;

    const size_t need = (size_t)N_QUERIES * NUM_LEVELS * 2 * sizeof(float); // 128 MiB
    dim3 block(BLK);
    dim3 ggrid(NUM_LEVELS * BLOCKS_PER_LEVEL);

    if (ws_size >= need) {
        float* ws = (float*)d_ws;
        gather_kernel<true><<<ggrid, block, 0, stream>>>(in, emb, bptr, ws);
        transpose_kernel<<<N_QUERIES / BLK, block, 0, stream>>>(ws, out);
    } else {
        gather_kernel<false><<<ggrid, block, 0, stream>>>(in, emb, bptr, out);
    }
}